// Round 4
// baseline (1005.947 us; speedup 1.0000x reference)
//
#include <hip/hip_runtime.h>

// DeepRLSNet: batched RLS. B=64, N=T=2000, TAPS=64.
//
// R16 = R15 (942us; fused update+next-dots, 4-pair deep prefetch) with a
// BIT-IDENTICAL cross-barrier chain reorder:
//   pass1 (pre-barrier):  Q/QT dual rank-1 updates + fused exchange dots
//                         (nqx/nxq/nu/nv) -> reduces -> ds_write.
//   pass2 (post-barrier, next round): w dual rank-1 update + wy dots ->
//                         reduces. Executes right after the next round's
//                         slice ds_reads are ISSUED, filling the ~120cy
//                         LDS latency window with register-only work and
//                         removing ~90cy from every wave's pre-barrier tail.
// Also: pd0 chain computed+reduced first so den0->rcp->s0 overlaps the
// a/bb/c2 chains; x-prefetch moved out of the post-barrier latency window.
// All accumulator chains keep R15's exact internal op order (reordering
// between independent chains only) -> same bits. First-round pass2 uses
// zero-init carried state: fma(+0,+0,w)=w and the wy chains stay +0,
// bit-identical to R15's prologue.
// Canary: absmax must be exactly 0.015625.

#define B_ 64
#define N_ 2000
#define TAPS_ 64
#define STEPS_ 2000
#define VST_ 72   // padded LDS vector stride; banks r+8q -> 2-way max (free)

typedef float f2 __attribute__((ext_vector_type(2)));

__device__ __forceinline__ f2 pk2(float v) { f2 r; r.x = v; r.y = v; return r; }

__device__ __forceinline__ void lds_barrier() {
    // LDS-only fence + barrier: global (vmcnt) prefetch stays in flight.
    asm volatile("s_waitcnt lgkmcnt(0)\n\ts_barrier" ::: "memory");
}

__device__ __forceinline__ float clipl(float v) {
    return fminf(fmaxf(v, 1e-4f), 0.9999f);
}

// sum over the 4 q-lanes of a quad via DPP quad_perm (identical to R15).
__device__ __forceinline__ float quad_reduce(float v) {
    int t1 = __builtin_amdgcn_update_dpp(__float_as_int(v), __float_as_int(v),
                                         0xB1, 0xF, 0xF, false);   // xor 1
    v += __int_as_float(t1);
    int t2 = __builtin_amdgcn_update_dpp(__float_as_int(v), __float_as_int(v),
                                         0x4E, 0xF, 0xF, false);   // xor 2
    v += __int_as_float(t2);
    return v;   // bitwise-identical in all 4 lanes of the quad
}

// 1/v via v_rcp_f32 + one Newton step (~0.5 ulp). Identical to R15.
__device__ __forceinline__ float rcp_nr(float v) {
    float r = __builtin_amdgcn_rcpf(v);
    float e = fmaf(-v, r, 1.0f);
    return fmaf(r, e, r);
}

__global__ __launch_bounds__(256, 1) void rls_kernel(
    const float* __restrict__ x_seq,   // [B, N, TAPS]
    const float* __restrict__ d_seq,   // [B, N]
    const float* __restrict__ lambdas, // [T]
    float* __restrict__ y_out,         // [B, N]
    float* __restrict__ w_out)         // [B, TAPS]
{
    const int b   = blockIdx.x;
    const int tid = threadIdx.x;
    const int r   = tid >> 2;    // row 0..63
    const int q   = tid & 3;     // quarter 0..3
    const int qb  = q << 4;

    // [parity][vec][VST_], vec: 0=Qx 1=xQ 2=u 3=v  (R12/R15 layout)
    __shared__ __align__(16) float  bufs[2][4][VST_];
    __shared__ __align__(16) float  d_lds[STEPS_];
    __shared__ __align__(16) float2 lam2[STEPS_];   // {clip(lam), rcp_nr(clip(lam))}

    const float* xb = x_seq + (size_t)b * N_ * TAPS_;
    const float* db = d_seq + (size_t)b * N_;

    for (int idx = tid; idx < STEPS_; idx += 256) {
        d_lds[idx] = db[idx];
        const float lc = clipl(lambdas[idx]);
        lam2[idx] = make_float2(lc, rcp_nr(lc));
    }

    f2 Q[8], QT[8], w[8];
    #pragma unroll
    for (int j = 0; j < 8; ++j) {
        Q[j].x = (qb + 2*j     == r) ? 1.0f : 0.0f;
        Q[j].y = (qb + 2*j + 1 == r) ? 1.0f : 0.0f;
        QT[j] = Q[j];
        w[j]  = pk2(0.0f);
    }
    float sig = 1.0f;   // P = sig * Q

    auto unpack4 = [](f2* dst, float4 v) {
        dst[0].x = v.x; dst[0].y = v.y; dst[1].x = v.z; dst[1].y = v.w;
    };

    auto loadpair = [&](f2 (&dA)[8], f2 (&dB)[8], int row) {
        const float4* v0 = (const float4*)(xb + (size_t)row * TAPS_ + qb);
        const float4* v1 = (const float4*)(xb + (size_t)(row + 1) * TAPS_ + qb);
        #pragma unroll
        for (int j4 = 0; j4 < 4; ++j4) {
            unpack4(&dA[2*j4], v0[j4]);
            unpack4(&dB[2*j4], v1[j4]);
        }
    };

    // 4 rotating row-pairs (R15 rotation). Round k: x=pair k&3, xn=(k+1)&3,
    // prefetch rows t+6,t+7 into pair (k+3)&3.
    f2 P0a[8], P0b[8], P1a[8], P1b[8], P2a[8], P2b[8], P3a[8], P3b[8];
    loadpair(P0a, P0b, 0);
    loadpair(P1a, P1b, 2);
    loadpair(P2a, P2b, 4);

    // loop-carried reduced row values (produced by prologue / pass1 fusion).
    float qxrS, xqrS, urS, vrS;
    float wy0S, wy1S;   // produced each round by pass2

    // carried pass2 state (w update deferred across the barrier).
    f2 Qxq_p[8], Qx1_p[8];
    f2 es0v_p = pk2(0.0f), es1v_p = pk2(0.0f);
    #pragma unroll
    for (int j = 0; j < 8; ++j) { Qxq_p[j] = pk2(0.0f); Qx1_p[j] = pk2(0.0f); }

    // ---- prologue: round 0's exchange data, R15 pre-phase bit-for-bit ----
    {
        f2 qx2 = pk2(0.f), xq2 = pk2(0.f), u2 = pk2(0.f), v2 = pk2(0.f);
        #pragma unroll
        for (int j = 0; j < 8; ++j) {
            qx2 = __builtin_elementwise_fma(Q[j],  P0a[j], qx2);
            xq2 = __builtin_elementwise_fma(QT[j], P0a[j], xq2);
            u2  = __builtin_elementwise_fma(Q[j],  P0b[j], u2);
            v2  = __builtin_elementwise_fma(QT[j], P0b[j], v2);
        }
        qxrS = quad_reduce(qx2.x + qx2.y);
        xqrS = quad_reduce(xq2.x + xq2.y);
        urS  = quad_reduce(u2.x + u2.y);
        vrS  = quad_reduce(v2.x + v2.y);
        bufs[0][q][r] = (q == 0) ? qxrS : (q == 1) ? xqrS : (q == 2) ? urS : vrS;
        // wy for round 0 comes from pass2's zero-init carried state (+0 bits).
    }

    auto round = [&](int t, f2 (&x0)[8], f2 (&x1)[8],
                     f2 (&xn0)[8], f2 (&xn1)[8],
                     f2 (&xf0)[8], f2 (&xf1)[8],
                     int par, bool pf, bool fuse)
    {
        lds_barrier();   // exchange data (written last round) visible

        // ---- issue slice ds_reads FIRST (p0 first: feeds the pd chain) ----
        f2 Qxq[8], xQq[8], uq[8], vq[8];
        {
            const float4* p0 = (const float4*)(&bufs[par][0][qb]);
            const float4* p1 = (const float4*)(&bufs[par][1][qb]);
            const float4* p2 = (const float4*)(&bufs[par][2][qb]);
            const float4* p3 = (const float4*)(&bufs[par][3][qb]);
            #pragma unroll
            for (int j4 = 0; j4 < 4; ++j4) {
                unpack4(&Qxq[2*j4], p0[j4]);
                unpack4(&xQq[2*j4], p1[j4]);
                unpack4(&uq [2*j4], p2[j4]);
                unpack4(&vq [2*j4], p3[j4]);
            }
        }
        const float2 l0 = lam2[t];
        const float2 l1 = lam2[t + 1];
        const float2 dd = *(const float2*)&d_lds[t];

        // ---- pass2 (register-only, fills the ds_read latency window):
        //      pending w update from last round + this round's wy dots ----
        f2 nw0 = pk2(0.f), nw1 = pk2(0.f);
        #pragma unroll
        for (int j = 0; j < 8; ++j) {
            w[j] = __builtin_elementwise_fma(Qxq_p[j], es0v_p, w[j]);
            w[j] = __builtin_elementwise_fma(Qx1_p[j], es1v_p, w[j]);
            nw0  = __builtin_elementwise_fma(w[j], x0[j], nw0);
            nw1  = __builtin_elementwise_fma(w[j], x1[j], nw1);
        }
        wy0S = quad_reduce(nw0.x + nw0.y);
        wy1S = quad_reduce(nw1.x + nw1.y);

        // ---- post-dots: pd chain first so den0->rcp->s0 overlaps a/bb/c2 ----
        f2 pd2 = pk2(0.f);
        #pragma unroll
        for (int j = 0; j < 8; ++j)
            pd2 = __builtin_elementwise_fma(x0[j], Qxq[j], pd2);
        const float pd0  = quad_reduce(pd2.x + pd2.y);
        const float den0 = fmaf(sig, pd0, l0.x);
        const float s0   = sig * rcp_nr(den0);

        f2 a2 = pk2(0.f), bb2 = pk2(0.f), c22 = pk2(0.f);
        #pragma unroll
        for (int j = 0; j < 8; ++j) {
            a2  = __builtin_elementwise_fma(x1[j], xQq[j], a2);
            bb2 = __builtin_elementwise_fma(x1[j], Qxq[j], bb2);
            c22 = __builtin_elementwise_fma(x1[j], uq[j],  c22);
        }
        const float a   = quad_reduce(a2.x + a2.y);
        const float bb  = quad_reduce(bb2.x + bb2.y);
        const float c2  = quad_reduce(c22.x + c22.y);

        // ---- scalars (R15 op order) ----
        const float err0 = dd.x - wy0S;
        const float es0  = s0 * err0;
        const float sa   = s0 * a;
        const float sb   = s0 * bb;

        const float sig1 = sig * l0.y;
        const float pd1  = fmaf(-sa, bb, c2);
        const float den1 = fmaf(sig1, pd1, l1.x);
        const float s1   = sig1 * rcp_nr(den1);
        const float y1   = fmaf(es0, bb, wy1S);
        const float err1 = dd.y - y1;
        const float es1  = s1 * err1;
        sig = sig1 * l1.y;

        if (tid == 0)
            *(float2*)(y_out + (size_t)b * N_ + t) = make_float2(wy0S, y1);

        // ---- deep prefetch moved here (issue-heavy region, off the
        //      latency-critical post-barrier window) ----
        if (pf) loadpair(xf0, xf1, t + 6);

        // ---- pass1: Q/QT dual rank-1 updates + fused exchange dots ----
        const float qx1r = fmaf(-sa, qxrS, urS);
        const float xq1r = fmaf(-sb, xqrS, vrS);
        const f2 nsa   = pk2(-sa);
        const f2 nsb   = pk2(-sb);
        const f2 s0v   = pk2(s0);
        const f2 s1v   = pk2(s1);
        const f2 ntr0  = pk2(-(s0 * qxrS));
        const f2 ntr1  = pk2(-(s1 * qx1r));
        const f2 nxqr  = pk2(-xqrS);
        const f2 nxq1r = pk2(-xq1r);

        f2 nqx = pk2(0.f), nxq = pk2(0.f), nu = pk2(0.f), nv = pk2(0.f);

        #pragma unroll
        for (int j = 0; j < 8; ++j) {
            const f2 Qx1 = __builtin_elementwise_fma(nsa, Qxq[j], uq[j]);
            const f2 xQ1 = __builtin_elementwise_fma(nsb, xQq[j], vq[j]);
            const f2 tq0 = s0v * Qxq[j];
            const f2 tq1 = s1v * Qx1;
            // Q row r: subtract both outer-product terms (R15 chain bits)
            Q[j] = __builtin_elementwise_fma(ntr0, xQq[j], Q[j]);
            Q[j] = __builtin_elementwise_fma(ntr1, xQ1,    Q[j]);
            // QT row r (= Q column r): transposed products, identical bits
            QT[j] = __builtin_elementwise_fma(tq0, nxqr,  QT[j]);
            QT[j] = __builtin_elementwise_fma(tq1, nxq1r, QT[j]);
            // fused next-round exchange dots on the freshly updated regs
            if (fuse) {
                nqx = __builtin_elementwise_fma(Q[j],  xn0[j], nqx);
                nxq = __builtin_elementwise_fma(QT[j], xn0[j], nxq);
                nu  = __builtin_elementwise_fma(Q[j],  xn1[j], nu);
                nv  = __builtin_elementwise_fma(QT[j], xn1[j], nv);
            }
            // carry for next round's pass2 (deferred w update)
            Qxq_p[j] = Qxq[j];
            Qx1_p[j] = Qx1;
        }
        es0v_p = pk2(es0);
        es1v_p = pk2(es1);

        if (fuse) {
            qxrS = quad_reduce(nqx.x + nqx.y);
            xqrS = quad_reduce(nxq.x + nxq.y);
            urS  = quad_reduce(nu.x + nu.y);
            vrS  = quad_reduce(nv.x + nv.y);
            bufs[par ^ 1][q][r] =
                (q == 0) ? qxrS : (q == 1) ? xqrS : (q == 2) ? urS : vrS;
        }
    };

    // main loop: rounds k=0..995 (t=0..1990), 4-round unroll for pair rotation.
    for (int t = 0; t < 1992; t += 8) {
        round(t + 0, P0a, P0b, P1a, P1b, P3a, P3b, 0, true, true);
        round(t + 2, P1a, P1b, P2a, P2b, P0a, P0b, 1, true, true);
        round(t + 4, P2a, P2b, P3a, P3b, P1a, P1b, 0, true, true);
        round(t + 6, P3a, P3b, P0a, P0b, P2a, P2b, 1, true, true);
    }
    // tail (same flags as R15)
    round(1992, P0a, P0b, P1a, P1b, P3a, P3b, 0, true,  true);
    round(1994, P1a, P1b, P2a, P2b, P0a, P0b, 1, false, true);
    round(1996, P2a, P2b, P3a, P3b, P1a, P1b, 0, false, true);
    round(1998, P3a, P3b, P0a, P0b, P2a, P2b, 1, false, false);

    // ---- epilogue: apply round 999's pending w update ----
    #pragma unroll
    for (int j = 0; j < 8; ++j) {
        w[j] = __builtin_elementwise_fma(Qxq_p[j], es0v_p, w[j]);
        w[j] = __builtin_elementwise_fma(Qx1_p[j], es1v_p, w[j]);
    }

    // ---- final weights: row-group 0 holds a full replica across q ----
    if (r == 0) {
        float4* wo = (float4*)(w_out + (size_t)b * TAPS_ + qb);
        #pragma unroll
        for (int j4 = 0; j4 < 4; ++j4)
            wo[j4] = make_float4(w[2*j4].x, w[2*j4].y, w[2*j4+1].x, w[2*j4+1].y);
    }
}

extern "C" void kernel_launch(void* const* d_in, const int* in_sizes, int n_in,
                              void* d_out, int out_size, void* d_ws, size_t ws_size,
                              hipStream_t stream) {
    const float* x_seq   = (const float*)d_in[0];
    const float* d_seq   = (const float*)d_in[1];
    const float* lambdas = (const float*)d_in[2];

    float* y_out = (float*)d_out;                      // B*N floats
    float* w_out = (float*)d_out + (size_t)B_ * N_;    // B*TAPS floats

    rls_kernel<<<B_, 256, 0, stream>>>(x_seq, d_seq, lambdas, y_out, w_out);
}

// Round 5
// 909.596 us; speedup vs baseline: 1.1059x; 1.1059x over previous
//
#include <hip/hip_runtime.h>

// DeepRLSNet: batched RLS. B=64, N=T=2000, TAPS=64.
//
// R17 = R15 (942us best; fused update+next-dots, 4-pair deep prefetch) with
// BIT-IDENTICAL round-top reordering ONLY (R16's w-deferral reverted — it
// added ~150cy/round of stall via the post-barrier wy chain + carried regs):
//  (a) slice ds_reads split in two groups interleaved with their consumers:
//      {Qxq,xQq} -> pd chain -> {uq,vq} -> a/bb chains -> c2 chain.
//      Encourages fine-grained lgkmcnt waits; vq's read issues well before
//      its s1-gated consumer (pass1 update loop).
//  (b) pd-first scalars: den0->rcp->s0 hoisted right after the pd reduce,
//      overlapping the a/bb/c2 chains (R16's good idea, isolated).
//  (c) lam2[t],lam2[t+1] fused into one b128 read (t always even; same bits).
// All accumulator chains keep R15's exact internal op order; only ordering
// BETWEEN independent chains changed -> output bits unchanged.
// Canary: absmax must be exactly 0.015625.

#define B_ 64
#define N_ 2000
#define TAPS_ 64
#define STEPS_ 2000
#define VST_ 72   // padded LDS vector stride; banks r+8q -> 2-way max (free)

typedef float f2 __attribute__((ext_vector_type(2)));

__device__ __forceinline__ f2 pk2(float v) { f2 r; r.x = v; r.y = v; return r; }

__device__ __forceinline__ void lds_barrier() {
    // LDS-only fence + barrier: global (vmcnt) prefetch stays in flight.
    asm volatile("s_waitcnt lgkmcnt(0)\n\ts_barrier" ::: "memory");
}

__device__ __forceinline__ float clipl(float v) {
    return fminf(fmaxf(v, 1e-4f), 0.9999f);
}

// sum over the 4 q-lanes of a quad via DPP quad_perm (identical to R15).
__device__ __forceinline__ float quad_reduce(float v) {
    int t1 = __builtin_amdgcn_update_dpp(__float_as_int(v), __float_as_int(v),
                                         0xB1, 0xF, 0xF, false);   // xor 1
    v += __int_as_float(t1);
    int t2 = __builtin_amdgcn_update_dpp(__float_as_int(v), __float_as_int(v),
                                         0x4E, 0xF, 0xF, false);   // xor 2
    v += __int_as_float(t2);
    return v;   // bitwise-identical in all 4 lanes of the quad
}

// 1/v via v_rcp_f32 + one Newton step (~0.5 ulp). Identical to R15.
__device__ __forceinline__ float rcp_nr(float v) {
    float r = __builtin_amdgcn_rcpf(v);
    float e = fmaf(-v, r, 1.0f);
    return fmaf(r, e, r);
}

__global__ __launch_bounds__(256, 1) void rls_kernel(
    const float* __restrict__ x_seq,   // [B, N, TAPS]
    const float* __restrict__ d_seq,   // [B, N]
    const float* __restrict__ lambdas, // [T]
    float* __restrict__ y_out,         // [B, N]
    float* __restrict__ w_out)         // [B, TAPS]
{
    const int b   = blockIdx.x;
    const int tid = threadIdx.x;
    const int r   = tid >> 2;    // row 0..63
    const int q   = tid & 3;     // quarter 0..3
    const int qb  = q << 4;

    // [parity][vec][VST_], vec: 0=Qx 1=xQ 2=u 3=v  (R12/R15 layout)
    __shared__ __align__(16) float  bufs[2][4][VST_];
    __shared__ __align__(16) float  d_lds[STEPS_];
    __shared__ __align__(16) float2 lam2[STEPS_];   // {clip(lam), rcp_nr(clip(lam))}

    const float* xb = x_seq + (size_t)b * N_ * TAPS_;
    const float* db = d_seq + (size_t)b * N_;

    for (int idx = tid; idx < STEPS_; idx += 256) {
        d_lds[idx] = db[idx];
        const float lc = clipl(lambdas[idx]);
        lam2[idx] = make_float2(lc, rcp_nr(lc));
    }

    f2 Q[8], QT[8], w[8];
    #pragma unroll
    for (int j = 0; j < 8; ++j) {
        Q[j].x = (qb + 2*j     == r) ? 1.0f : 0.0f;
        Q[j].y = (qb + 2*j + 1 == r) ? 1.0f : 0.0f;
        QT[j] = Q[j];
        w[j]  = pk2(0.0f);
    }
    float sig = 1.0f;   // P = sig * Q

    auto unpack4 = [](f2* dst, float4 v) {
        dst[0].x = v.x; dst[0].y = v.y; dst[1].x = v.z; dst[1].y = v.w;
    };

    auto loadpair = [&](f2 (&dA)[8], f2 (&dB)[8], int row) {
        const float4* v0 = (const float4*)(xb + (size_t)row * TAPS_ + qb);
        const float4* v1 = (const float4*)(xb + (size_t)(row + 1) * TAPS_ + qb);
        #pragma unroll
        for (int j4 = 0; j4 < 4; ++j4) {
            unpack4(&dA[2*j4], v0[j4]);
            unpack4(&dB[2*j4], v1[j4]);
        }
    };

    // 4 rotating row-pairs (R15 rotation). Round k: x=pair k&3, xn=(k+1)&3,
    // prefetch rows t+6,t+7 into pair (k+3)&3.
    f2 P0a[8], P0b[8], P1a[8], P1b[8], P2a[8], P2b[8], P3a[8], P3b[8];
    loadpair(P0a, P0b, 0);
    loadpair(P1a, P1b, 2);
    loadpair(P2a, P2b, 4);

    // loop-carried reduced row values (produced by prologue / fused phase).
    float qxrS, xqrS, urS, vrS, wy0S, wy1S;

    // ---- prologue: round 0's exchange data, R15 pre-phase bit-for-bit ----
    {
        f2 qx2 = pk2(0.f), xq2 = pk2(0.f), u2 = pk2(0.f), v2 = pk2(0.f);
        #pragma unroll
        for (int j = 0; j < 8; ++j) {
            qx2 = __builtin_elementwise_fma(Q[j],  P0a[j], qx2);
            xq2 = __builtin_elementwise_fma(QT[j], P0a[j], xq2);
            u2  = __builtin_elementwise_fma(Q[j],  P0b[j], u2);
            v2  = __builtin_elementwise_fma(QT[j], P0b[j], v2);
        }
        qxrS = quad_reduce(qx2.x + qx2.y);
        xqrS = quad_reduce(xq2.x + xq2.y);
        urS  = quad_reduce(u2.x + u2.y);
        vrS  = quad_reduce(v2.x + v2.y);
        bufs[0][q][r] = (q == 0) ? qxrS : (q == 1) ? xqrS : (q == 2) ? urS : vrS;

        f2 wy02 = pk2(0.f), wy12 = pk2(0.f);
        #pragma unroll
        for (int j = 0; j < 8; ++j) {
            wy02 = __builtin_elementwise_fma(w[j], P0a[j], wy02);
            wy12 = __builtin_elementwise_fma(w[j], P0b[j], wy12);
        }
        wy0S = quad_reduce(wy02.x + wy02.y);
        wy1S = quad_reduce(wy12.x + wy12.y);
    }

    auto round = [&](int t, f2 (&x0)[8], f2 (&x1)[8],
                     f2 (&xn0)[8], f2 (&xn1)[8],
                     f2 (&xf0)[8], f2 (&xf1)[8],
                     int par, bool pf, bool fuse)
    {
        lds_barrier();   // exchange data (written last round) visible

        // ---- read group 1: Qxq, xQq (feed pd / a,bb chains) ----
        f2 Qxq[8], xQq[8];
        {
            const float4* p0 = (const float4*)(&bufs[par][0][qb]);
            const float4* p1 = (const float4*)(&bufs[par][1][qb]);
            #pragma unroll
            for (int j4 = 0; j4 < 4; ++j4) {
                unpack4(&Qxq[2*j4], p0[j4]);
                unpack4(&xQq[2*j4], p1[j4]);
            }
        }
        // lam pair fused to one b128 (t even -> 16B aligned; same bits).
        const float4 lf = *(const float4*)&lam2[t];   // {l0.x,l0.y,l1.x,l1.y}
        const float2 dd = *(const float2*)&d_lds[t];

        // ---- deep prefetch (global pipe; fills the DS-latency window) ----
        if (pf) loadpair(xf0, xf1, t + 6);

        // ---- pd chain first, then den0->rcp->s0 early (overlaps a/bb/c2) ----
        f2 pd2 = pk2(0.f);
        #pragma unroll
        for (int j = 0; j < 8; ++j)
            pd2 = __builtin_elementwise_fma(x0[j], Qxq[j], pd2);
        const float pd0  = quad_reduce(pd2.x + pd2.y);
        const float den0 = fmaf(sig, pd0, lf.x);
        const float s0   = sig * rcp_nr(den0);

        // ---- read group 2: uq, vq (c2 chain; update loop) ----
        f2 uq[8], vq[8];
        {
            const float4* p2 = (const float4*)(&bufs[par][2][qb]);
            const float4* p3 = (const float4*)(&bufs[par][3][qb]);
            #pragma unroll
            for (int j4 = 0; j4 < 4; ++j4) {
                unpack4(&uq[2*j4], p2[j4]);
                unpack4(&vq[2*j4], p3[j4]);
            }
        }

        // ---- a, bb chains (group-1 data), then c2 (group-2 data) ----
        f2 a2 = pk2(0.f), bb2 = pk2(0.f);
        #pragma unroll
        for (int j = 0; j < 8; ++j) {
            a2  = __builtin_elementwise_fma(x1[j], xQq[j], a2);
            bb2 = __builtin_elementwise_fma(x1[j], Qxq[j], bb2);
        }
        const float a  = quad_reduce(a2.x + a2.y);
        const float bb = quad_reduce(bb2.x + bb2.y);

        f2 c22 = pk2(0.f);
        #pragma unroll
        for (int j = 0; j < 8; ++j)
            c22 = __builtin_elementwise_fma(x1[j], uq[j], c22);
        const float c2 = quad_reduce(c22.x + c22.y);

        // ---- scalars (R15 op order for everything downstream of s0) ----
        const float err0 = dd.x - wy0S;
        const float es0  = s0 * err0;
        const float sa   = s0 * a;
        const float sb   = s0 * bb;

        const float sig1 = sig * lf.y;
        const float pd1  = fmaf(-sa, bb, c2);
        const float den1 = fmaf(sig1, pd1, lf.z);
        const float s1   = sig1 * rcp_nr(den1);
        const float y1   = fmaf(es0, bb, wy1S);
        const float err1 = dd.y - y1;
        const float es1  = s1 * err1;
        sig = sig1 * lf.w;

        if (tid == 0)
            *(float2*)(y_out + (size_t)b * N_ + t) = make_float2(wy0S, y1);

        // ---- pass1: dual rank-1 updates fused with next-dots (R15 bits) ----
        const float qx1r = fmaf(-sa, qxrS, urS);
        const float xq1r = fmaf(-sb, xqrS, vrS);
        const f2 nsa   = pk2(-sa);
        const f2 nsb   = pk2(-sb);
        const f2 s0v   = pk2(s0);
        const f2 s1v   = pk2(s1);
        const f2 es0v  = pk2(es0);
        const f2 es1v  = pk2(es1);
        const f2 ntr0  = pk2(-(s0 * qxrS));
        const f2 ntr1  = pk2(-(s1 * qx1r));
        const f2 nxqr  = pk2(-xqrS);
        const f2 nxq1r = pk2(-xq1r);

        f2 nqx = pk2(0.f), nxq = pk2(0.f), nu = pk2(0.f), nv = pk2(0.f);
        f2 nw0 = pk2(0.f), nw1 = pk2(0.f);

        #pragma unroll
        for (int j = 0; j < 8; ++j) {
            const f2 Qx1 = __builtin_elementwise_fma(nsa, Qxq[j], uq[j]);
            const f2 xQ1 = __builtin_elementwise_fma(nsb, xQq[j], vq[j]);
            const f2 tq0 = s0v * Qxq[j];
            const f2 tq1 = s1v * Qx1;
            // w: two honest rank-1 adds
            w[j] = __builtin_elementwise_fma(Qxq[j], es0v, w[j]);
            w[j] = __builtin_elementwise_fma(Qx1,    es1v, w[j]);
            // Q row r: subtract both outer-product terms
            Q[j] = __builtin_elementwise_fma(ntr0, xQq[j], Q[j]);
            Q[j] = __builtin_elementwise_fma(ntr1, xQ1,    Q[j]);
            // QT row r (= Q column r): transposed products, identical bits
            QT[j] = __builtin_elementwise_fma(tq0, nxqr,  QT[j]);
            QT[j] = __builtin_elementwise_fma(tq1, nxq1r, QT[j]);
            // fused next-round pre-dots on the freshly updated registers
            if (fuse) {
                nqx = __builtin_elementwise_fma(Q[j],  xn0[j], nqx);
                nxq = __builtin_elementwise_fma(QT[j], xn0[j], nxq);
                nu  = __builtin_elementwise_fma(Q[j],  xn1[j], nu);
                nv  = __builtin_elementwise_fma(QT[j], xn1[j], nv);
                nw0 = __builtin_elementwise_fma(w[j],  xn0[j], nw0);
                nw1 = __builtin_elementwise_fma(w[j],  xn1[j], nw1);
            }
        }

        if (fuse) {
            qxrS = quad_reduce(nqx.x + nqx.y);
            xqrS = quad_reduce(nxq.x + nxq.y);
            urS  = quad_reduce(nu.x + nu.y);
            vrS  = quad_reduce(nv.x + nv.y);
            bufs[par ^ 1][q][r] =
                (q == 0) ? qxrS : (q == 1) ? xqrS : (q == 2) ? urS : vrS;
            wy0S = quad_reduce(nw0.x + nw0.y);
            wy1S = quad_reduce(nw1.x + nw1.y);
        }
    };

    // main loop: rounds k=0..995 (t=0..1990), 4-round unroll for pair rotation.
    for (int t = 0; t < 1992; t += 8) {
        round(t + 0, P0a, P0b, P1a, P1b, P3a, P3b, 0, true, true);
        round(t + 2, P1a, P1b, P2a, P2b, P0a, P0b, 1, true, true);
        round(t + 4, P2a, P2b, P3a, P3b, P1a, P1b, 0, true, true);
        round(t + 6, P3a, P3b, P0a, P0b, P2a, P2b, 1, true, true);
    }
    // tail (same flags as R15)
    round(1992, P0a, P0b, P1a, P1b, P3a, P3b, 0, true,  true);
    round(1994, P1a, P1b, P2a, P2b, P0a, P0b, 1, false, true);
    round(1996, P2a, P2b, P3a, P3b, P1a, P1b, 0, false, true);
    round(1998, P3a, P3b, P0a, P0b, P2a, P2b, 1, false, false);

    // ---- final weights: row-group 0 holds a full replica across q ----
    if (r == 0) {
        float4* wo = (float4*)(w_out + (size_t)b * TAPS_ + qb);
        #pragma unroll
        for (int j4 = 0; j4 < 4; ++j4)
            wo[j4] = make_float4(w[2*j4].x, w[2*j4].y, w[2*j4+1].x, w[2*j4+1].y);
    }
}

extern "C" void kernel_launch(void* const* d_in, const int* in_sizes, int n_in,
                              void* d_out, int out_size, void* d_ws, size_t ws_size,
                              hipStream_t stream) {
    const float* x_seq   = (const float*)d_in[0];
    const float* d_seq   = (const float*)d_in[1];
    const float* lambdas = (const float*)d_in[2];

    float* y_out = (float*)d_out;                      // B*N floats
    float* w_out = (float*)d_out + (size_t)B_ * N_;    // B*TAPS floats

    rls_kernel<<<B_, 256, 0, stream>>>(x_seq, d_seq, lambdas, y_out, w_out);
}